// Round 5
// baseline (92.146 us; speedup 1.0000x reference)
//
#include <hip/hip_runtime.h>
#include <math.h>

#define SS 8
#define CC 16
#define HH 64
#define WW 96
#define DD 64
#define NN (HH*WW)
#define PW 100            // padded width: 2 zero cols each side
#define PH 66             // padded height: 1 zero row each side
#define PN (PH*PW)        // 6600 padded pixels per source
#define TXC 12            // tiles in x
#define TYC 8             // tiles in y
#define NBLK ((DD/4)*TXC*TYC)   // 1536 cost blocks
#define NBOX (NBLK*SS)          // 12288 (block, source) boxes

typedef _Float16 h2 __attribute__((ext_vector_type(2)));
struct alignas(16) H8 { h2 v[4]; };   // 8 halfs = 16 B

typedef const __attribute__((address_space(1))) unsigned int gu32;
typedef __attribute__((address_space(3))) unsigned int lu32;

// Folded projection matrix for source s: mo[0..8]=3x3 (pix->ray), mo[9..11]=t.
__device__ __forceinline__ void compute_mat(int s, const float* Ks, const float* ext,
                                            const float* invK, float* mo)
{
    float P[3][4];
    for (int i = 0; i < 3; ++i)
        for (int j = 0; j < 4; ++j) {
            float a = 0.f;
            for (int k = 0; k < 4; ++k)
                a += Ks[s * 16 + i * 4 + k] * ext[s * 16 + k * 4 + j];
            P[i][j] = a;
        }
    for (int i = 0; i < 3; ++i) {
        for (int j = 0; j < 3; ++j) {
            float a = 0.f;
            for (int k = 0; k < 3; ++k)
                a += P[i][k] * invK[k * 4 + j];
            mo[i * 3 + j] = a;
        }
        mo[9 + i] = P[i][3];
    }
}

// Prep: (1) transpose+convert src -> f16 zero-padded channel-last (S,PH,PW,C),
// cur -> (H,W,C); (2) mats + 64 log depths; (3) per-(block,src) analytic tap
// bounding boxes. u,v are projective (monotone on segments, pz multilinear),
// so extrema over the tile x depth-group box are attained at the 8 corners;
// +-1 texel margin absorbs fp noise. Encoded: xlo|ylo<<7|fit<<14|skip<<15.
__global__ __launch_bounds__(256) void prep_kernel(
    const float* __restrict__ cur, const float* __restrict__ src,
    const float* __restrict__ ext, const float* __restrict__ Ks,
    const float* __restrict__ invK, const float* __restrict__ mnp,
    const float* __restrict__ mxp,
    _Float16* __restrict__ srcT, _Float16* __restrict__ curT,
    float* __restrict__ mats, float* __restrict__ depths,
    unsigned* __restrict__ boxes)
{
    int tid = blockIdx.x * 256 + threadIdx.x;
    const int srcPad = SS * PN;             // 52800
    if (tid < srcPad) {
        int s = tid / PN;
        int rem = tid % PN;
        int py = rem / PW;
        int px = rem % PW;
        _Float16 v[CC] = {};                // zeros for border texels
        if (py >= 1 && py <= HH && px >= 2 && px <= WW + 1) {
            int p = (py - 1) * WW + (px - 2);
            const float* base = src + (size_t)s * CC * NN + p;
#pragma unroll
            for (int c = 0; c < CC; ++c) v[c] = (_Float16)base[c * NN];
        }
        H8* o = (H8*)(srcT + (size_t)tid * CC);
        o[0] = *(H8*)&v[0];
        o[1] = *(H8*)&v[8];
    } else if (tid < srcPad + NN) {
        int p = tid - srcPad;
        const float* base = cur + p;
        _Float16 v[CC];
#pragma unroll
        for (int c = 0; c < CC; ++c) v[c] = (_Float16)base[c * NN];
        H8* o = (H8*)(curT + (size_t)p * CC);
        o[0] = *(H8*)&v[0];
        o[1] = *(H8*)&v[8];
    } else if (tid < srcPad + NN + NBOX) {
        int idx = tid - (srcPad + NN);
        int s   = idx & 7;
        int blk = idx >> 3;
        int dg  = blk / (TXC * TYC);
        int rem = blk % (TXC * TYC);
        int tyi = rem / TXC;
        int txi = rem % TXC;
        float mm[12];
        compute_mat(s, Ks, ext, invK, mm);
        float lmn = logf(mnp[0]);
        float lr  = logf(mxp[0] / mnp[0]);
        float D0 = expf(lmn + lr * ((float)(dg * 4)     * (1.0f / (DD - 1))));
        float D3 = expf(lmn + lr * ((float)(dg * 4 + 3) * (1.0f / (DD - 1))));
        float xs0 = txi * 8 + 0.5f, xs1 = txi * 8 + 7.5f;
        float ys0 = tyi * 8 + 0.5f, ys1 = tyi * 8 + 7.5f;
        float pzmin = 1e30f, pzmax = -1e30f;
        float umin = 1e30f, umax = -1e30f, vmin = 1e30f, vmax = -1e30f;
        int x0min = 999, x0max = -999, y0min = 999, y1max = -999;
        for (int ci = 0; ci < 8; ++ci) {
            float X  = (ci & 1) ? xs1 : xs0;
            float Y  = (ci & 2) ? ys1 : ys0;
            float Dp = (ci & 4) ? D3  : D0;
            float qx = mm[0] * X + mm[1] * Y + mm[2];
            float qy = mm[3] * X + mm[4] * Y + mm[5];
            float qz = mm[6] * X + mm[7] * Y + mm[8];
            float pz = Dp * qz + mm[11];
            pzmin = fminf(pzmin, pz); pzmax = fmaxf(pzmax, pz);
            float r = __builtin_amdgcn_rcpf(pz + 1e-8f);   // mirror px math
            float u = (Dp * qx + mm[9])  * r - 0.5f;
            float v = (Dp * qy + mm[10]) * r - 0.5f;
            umin = fminf(umin, u); umax = fmaxf(umax, u);
            vmin = fminf(vmin, v); vmax = fmaxf(vmax, v);
            float ucc = fminf(fmaxf(u, -2.0f), 96.5f);
            float vcc = fminf(fmaxf(v, -1.0f), 64.5f);
            int x0c = (int)floorf(ucc) + 2;
            int y0c = (int)floorf(vcc) + 1;
            int y1c = min(y0c + 1, PH - 1);
            x0min = min(x0min, x0c); x0max = max(x0max, x0c);
            y0min = min(y0min, y0c); y1max = max(y1max, y1c);
        }
        bool allpz = pzmin > 1e-3f;          // margin: interior fp-eval surely > 0
        bool skip  = (pzmax <= 0.f) ||
                     (allpz && (umax < -1.01f || umin > 96.01f ||
                                vmax < -1.01f || vmin > 64.01f));
        int xlo = 0, ylo = 0; bool fit = false;
        if (allpz) {
            xlo = max(x0min - 1, 0);         // -1: fp margin
            ylo = max(y0min - 1, 0);
            fit = (x0max + 2 - xlo <= 31)    // right tap + fp margin within 32 cols
               && (y1max + 1 - ylo <= 15);   // fp margin within 16 rows
        }
        boxes[idx] = (unsigned)xlo | ((unsigned)ylo << 7)
                   | (fit ? 1u << 14 : 0u) | (skip ? 1u << 15 : 0u);
    }
    if (blockIdx.x == 0) {
        if (threadIdx.x < DD) {
            float lmn = logf(mnp[0]);
            float lr  = logf(mxp[0] / mnp[0]);
            depths[threadIdx.x] = expf(lmn + lr * ((float)threadIdx.x * (1.0f / (DD - 1))));
        } else if (threadIdx.x < DD + SS) {
            int s = threadIdx.x - DD;
            float mm[12];
            compute_mat(s, Ks, ext, invK, mm);
            for (int i = 0; i < 12; ++i) mats[s * 12 + i] = mm[i];
        }
    }
}

// Main: block = 8x8 tile x 4 depths (one depth per wave). Per source: scalar
// box flags (precomputed) pick one of three uniform paths: skip (exact 0),
// staged (coalesced global_load_lds of a 16-row x 32-texel box -> quad-coop
// conflict-free LDS reads), or direct-gather fallback. Stage of s+1 is issued
// right after the sync and flies under compute(s) (one barrier per source).
__global__ __launch_bounds__(256, 4) void cost_kernel(
    const _Float16* __restrict__ curT, const _Float16* __restrict__ srcT,
    const float* __restrict__ mats, const float* __restrict__ depths,
    const unsigned* __restrict__ boxes, float* __restrict__ out)
{
    __shared__ H8 stage[2][16][64];        // 2 x 16 KB double buffer

    int tid = threadIdx.x;
    int bx = blockIdx.x;
    int dg  = bx / (TXC * TYC);
    int rem = bx % (TXC * TYC);
    int tyi = rem / TXC;
    int txi = rem % TXC;
    int lane = tid & 63;
    int dsub = tid >> 6;                   // wave index = depth sub-index
    int d  = dg * 4 + dsub;

    int g = lane >> 2;                     // pixel group 0..15 (2 tile rows x 8 cols)
    int q = lane & 3;                      // 16B chunk within the 64B tap-pair
    int px = txi * 8 + (g & 7);
    int rowp = g >> 3;
    float x = (float)px + 0.5f;
    float ybase = (float)(tyi * 8 + rowp) + 0.5f;   // +2 per item

    H8 cur16[4];                           // cur chunk (q&1) for this lane's 4 px
#pragma unroll
    for (int i = 0; i < 4; ++i) {
        int n = (tyi * 8 + i * 2 + rowp) * WW + px;
        cur16[i] = *(const H8*)(curT + (size_t)n * CC + (q & 1) * 8);
    }
    float depth = depths[__builtin_amdgcn_readfirstlane(d)];
    const unsigned* bb = boxes + (size_t)bx * SS;

    unsigned bcur = __builtin_amdgcn_readfirstlane(bb[0]);
    if ((bcur & (1u << 14)) && !(bcur & (1u << 15))) {   // prologue stage s=0
        int xlo = bcur & 127, ylo = (bcur >> 7) & 127;
#pragma unroll
        for (int k = 0; k < 4; ++k) {
            int row = dsub + 4 * k;
            const _Float16* grow = srcT + ((size_t)((ylo + row) * PW + xlo)) * CC;
            __builtin_amdgcn_global_load_lds((gu32*)(grow + (size_t)lane * 8),
                                             (lu32*)&stage[0][row][0], 16, 0, 0);
        }
    }

    float acc[4] = {0.f, 0.f, 0.f, 0.f};
#pragma unroll 1
    for (int s = 0; s < SS; ++s) {
        __syncthreads();                   // stage(s) complete; buf[(s+1)&1] free
        unsigned bnext = 0;
        if (s < SS - 1) {
            bnext = __builtin_amdgcn_readfirstlane(bb[s + 1]);
            if ((bnext & (1u << 14)) && !(bnext & (1u << 15))) {
                int xloN = bnext & 127, yloN = (bnext >> 7) & 127;
                const _Float16* sbN = srcT + (size_t)(s + 1) * (PN * CC);
#pragma unroll
                for (int k = 0; k < 4; ++k) {
                    int row = dsub + 4 * k;
                    const _Float16* grow = sbN + ((size_t)((yloN + row) * PW + xloN)) * CC;
                    __builtin_amdgcn_global_load_lds((gu32*)(grow + (size_t)lane * 8),
                                                     (lu32*)&stage[(s + 1) & 1][row][0], 16, 0, 0);
                }
            }
        }
        if (!(bcur & (1u << 15))) {        // not skipped
            const float* m = &mats[s * 12];
            float m0 = m[0], m1 = m[1], m2 = m[2], m3 = m[3], m4 = m[4], m5 = m[5];
            float m6 = m[6], m7 = m[7], m8 = m[8], m9 = m[9], m10 = m[10], m11 = m[11];
            float qx = m0 * x + m1 * ybase + m2;
            float qy = m3 * x + m4 * ybase + m5;
            float qz = m6 * x + m7 * ybase + m8;
            if (bcur & (1u << 14)) {
                // staged path: pz>0 for every px (corner-proven with margin)
                int xlo = bcur & 127, ylo = (bcur >> 7) & 127;
                int cb = s & 1;
#pragma unroll
                for (int i = 0; i < 4; ++i) {
                    float pz = depth * qz + m11;
                    float r = __builtin_amdgcn_rcpf(pz + 1e-8f);
                    float u = (depth * qx + m9)  * r - 0.5f;
                    float v = (depth * qy + m10) * r - 0.5f;
                    float uc = fminf(fmaxf(u, -2.0f), 96.5f);
                    float vc = fminf(fmaxf(v, -1.0f), 64.5f);
                    float x0f = floorf(uc), y0f = floorf(vc);
                    float wx = uc - x0f, wy = vc - y0f;
                    int x0p = (int)x0f + 2;
                    int y0p = (int)y0f + 1;
                    int y1p = min(y0p + 1, PH - 1);
                    int rx  = x0p - xlo;               // 0..30 by fit-check
                    int ry0 = y0p - ylo, ry1 = y1p - ylo;
                    H8 a = stage[cb][ry0][rx * 2 + q];
                    H8 b = stage[cb][ry1][rx * 2 + q];
                    float p0 = 0.f, p1 = 0.f;
#pragma unroll
                    for (int j = 0; j < 4; ++j) {
                        p0 = __builtin_amdgcn_fdot2(a.v[j], cur16[i].v[j], p0, false);
                        p1 = __builtin_amdgcn_fdot2(b.v[j], cur16[i].v[j], p1, false);
                    }
                    float t  = p0 + wy * (p1 - p0);
                    float wq = (q < 2) ? (1.f - wx) : wx;
                    acc[i] += wq * t;
                    qx += 2.f * m1; qy += 2.f * m4; qz += 2.f * m7;
                }
            } else {
                // fallback: direct global gathers (verified R3 path)
                const _Float16* sb = srcT + (size_t)s * (PN * CC);
#pragma unroll
                for (int i = 0; i < 4; ++i) {
                    float pz = depth * qz + m11;
                    bool ok = pz > 0.f;
                    float r = __builtin_amdgcn_rcpf(pz + 1e-8f);
                    float u = (depth * qx + m9)  * r - 0.5f;
                    float v = (depth * qy + m10) * r - 0.5f;
                    float uc = ok ? fminf(fmaxf(u, -2.0f), 96.5f) : -2.0f;
                    float vc = ok ? fminf(fmaxf(v, -1.0f), 64.5f) : -1.0f;
                    float x0f = floorf(uc), y0f = floorf(vc);
                    float wx = uc - x0f, wy = vc - y0f;
                    int x0p = (int)x0f + 2;
                    int y0p = (int)y0f + 1;
                    int y1p = min(y0p + 1, PH - 1);
                    const H8* t0 = (const H8*)(sb + (size_t)(y0p * PW + x0p) * CC) + q;
                    const H8* t1 = (const H8*)(sb + (size_t)(y1p * PW + x0p) * CC) + q;
                    H8 a = *t0, b = *t1;
                    float p0 = 0.f, p1 = 0.f;
#pragma unroll
                    for (int j = 0; j < 4; ++j) {
                        p0 = __builtin_amdgcn_fdot2(a.v[j], cur16[i].v[j], p0, false);
                        p1 = __builtin_amdgcn_fdot2(b.v[j], cur16[i].v[j], p1, false);
                    }
                    float t  = p0 + wy * (p1 - p0);
                    float wq = (q < 2) ? (1.f - wx) : wx;
                    acc[i] += wq * t;
                    qx += 2.f * m1; qy += 2.f * m4; qz += 2.f * m7;
                }
            }
        }
        bcur = bnext;
    }

    // quad reduction (masks 1,2 stay in-quad)
#pragma unroll
    for (int i = 0; i < 4; ++i) {
        acc[i] += __shfl_xor(acc[i], 1);
        acc[i] += __shfl_xor(acc[i], 2);
    }
    float val = acc[0];
    val = (q == 1) ? acc[1] : val;
    val = (q == 2) ? acc[2] : val;
    val = (q == 3) ? acc[3] : val;
    int py_w = tyi * 8 + (lane & 3) * 2 + (lane >> 5);
    int px_w = txi * 8 + ((lane >> 2) & 7);
    int n_w  = py_w * WW + px_w;
    out[(size_t)d * NN + n_w] = val;                       // cost_volume
    out[(size_t)DD * NN + (size_t)d * NN + n_w] = depth;   // depth_planes
}

extern "C" void kernel_launch(void* const* d_in, const int* in_sizes, int n_in,
                              void* d_out, int out_size, void* d_ws, size_t ws_size,
                              hipStream_t stream) {
    const float* cur  = (const float*)d_in[0];
    const float* src  = (const float*)d_in[1];
    const float* ext  = (const float*)d_in[2];
    const float* Ks   = (const float*)d_in[3];
    const float* invK = (const float*)d_in[4];
    const float* mn   = (const float*)d_in[5];
    const float* mx   = (const float*)d_in[6];
    float* out = (float*)d_out;

    char* ws = (char*)d_ws;
    _Float16* srcT = (_Float16*)ws;                     // S*PN*C halfs ≈ 1.69 MB
    _Float16* curT = srcT + (size_t)SS * PN * CC;       // N*C halfs
    float* mats    = (float*)(curT + (size_t)NN * CC);  // 96
    float* depths  = mats + SS * 12;                    // 64
    unsigned* boxes = (unsigned*)(depths + DD);         // 12288 u32 ≈ 48 KB

    int prepThreads = SS * PN + NN + NBOX;              // 71232
    int prepBlocks = (prepThreads + 255) / 256;         // 279
    prep_kernel<<<prepBlocks, 256, 0, stream>>>(cur, src, ext, Ks, invK, mn, mx,
                                                srcT, curT, mats, depths, boxes);
    cost_kernel<<<NBLK, 256, 0, stream>>>(curT, srcT, mats, depths, boxes, out);
}

// Round 6
// 81.869 us; speedup vs baseline: 1.1255x; 1.1255x over previous
//
#include <hip/hip_runtime.h>
#include <math.h>

#define SS 8
#define CC 16
#define HH 64
#define WW 96
#define DD 64
#define NN (HH*WW)
#define PW 100            // padded width: 2 zero cols each side
#define PH 66             // padded height: 1 zero row each side
#define PN (PH*PW)        // 6600 padded pixels per source

typedef _Float16 h2 __attribute__((ext_vector_type(2)));
struct alignas(16) H8 { h2 v[4]; };   // 8 halfs = 16 B

// Prep: transpose+convert src (S,C,H,W) -> f16 zero-padded channel-last
// (S, PH, PW, C); cur (C,H,W) -> f16 (H,W,C). Border texels written as zeros
// so OOB bilinear taps read 0 with no per-tap masking in the main kernel.
// Also folded projection matrices and the 64 log-spaced depths.
__global__ __launch_bounds__(256) void prep_kernel(
    const float* __restrict__ cur, const float* __restrict__ src,
    const float* __restrict__ ext, const float* __restrict__ Ks,
    const float* __restrict__ invK, const float* __restrict__ mnp,
    const float* __restrict__ mxp,
    _Float16* __restrict__ srcT, _Float16* __restrict__ curT,
    float* __restrict__ mats, float* __restrict__ depths)
{
    int tid = blockIdx.x * 256 + threadIdx.x;
    const int srcPad = SS * PN;             // 52800
    if (tid < srcPad) {
        int s = tid / PN;
        int rem = tid % PN;
        int py = rem / PW;
        int px = rem % PW;
        _Float16 v[CC] = {};                // zeros for border texels
        if (py >= 1 && py <= HH && px >= 2 && px <= WW + 1) {
            int p = (py - 1) * WW + (px - 2);
            const float* base = src + (size_t)s * CC * NN + p;
#pragma unroll
            for (int c = 0; c < CC; ++c) v[c] = (_Float16)base[c * NN];
        }
        H8* o = (H8*)(srcT + (size_t)tid * CC);
        o[0] = *(H8*)&v[0];
        o[1] = *(H8*)&v[8];
    } else if (tid < srcPad + NN) {
        int p = tid - srcPad;
        const float* base = cur + p;
        _Float16 v[CC];
#pragma unroll
        for (int c = 0; c < CC; ++c) v[c] = (_Float16)base[c * NN];
        H8* o = (H8*)(curT + (size_t)p * CC);
        o[0] = *(H8*)&v[0];
        o[1] = *(H8*)&v[8];
    }
    if (blockIdx.x == 0) {
        if (threadIdx.x < DD) {
            float lmn = logf(mnp[0]);
            float lr  = logf(mxp[0] / mnp[0]);
            depths[threadIdx.x] = expf(lmn + lr * ((float)threadIdx.x * (1.0f / (DD - 1))));
        } else if (threadIdx.x < DD + SS) {
            int s = threadIdx.x - DD;
            float P[3][4];
            for (int i = 0; i < 3; ++i)
                for (int j = 0; j < 4; ++j) {
                    float a = 0.f;
                    for (int k = 0; k < 4; ++k)
                        a += Ks[s * 16 + i * 4 + k] * ext[s * 16 + k * 4 + j];
                    P[i][j] = a;
                }
            for (int i = 0; i < 3; ++i) {
                for (int j = 0; j < 3; ++j) {
                    float a = 0.f;
                    for (int k = 0; k < 3; ++k)
                        a += P[i][k] * invK[k * 4 + j];
                    mats[s * 12 + i * 3 + j] = a;
                }
                mats[s * 12 + 9 + i] = P[i][3];
            }
        }
    }
}

// Main: verified R0 structure (block = 8x8 pixel tile x 4 depths, one depth
// per wave, 8 direct 16B gathers + 16 fdot2 per source, per-lane zero-border
// clamps). Cross-round evidence (R0/R4 @24 waves/CU = 38us; R3/R5 @16 = 47us
// across three different memory structures) says the kernel is LATENCY-bound,
// occupancy-controlled. ONLY change vs R0: __launch_bounds__(256, 8) (VGPR
// cap 64 -> 8 waves/SIMD = 32 waves/CU) + unroll 1 on the source loop so the
// live staging registers (8x H8 = 32 VGPR) fit the 64-VGPR budget.
__global__ __launch_bounds__(256, 8) void cost_kernel(
    const _Float16* __restrict__ curT, const _Float16* __restrict__ srcT,
    const float* __restrict__ mats, const float* __restrict__ depths,
    float* __restrict__ out)
{
    int tid = threadIdx.x;
    const int TX = WW / 8;                 // 12
    const int TY = HH / 8;                 // 8
    int bx = blockIdx.x;
    int dg  = bx / (TX * TY);              // 0..15
    int rem = bx % (TX * TY);
    int tyi = rem / TX;
    int txi = rem % TX;
    int lane = tid & 63;
    int dsub = tid >> 6;                   // wave index = depth sub-index
    int d  = dg * 4 + dsub;
    int px = txi * 8 + (lane & 7);
    int py = tyi * 8 + (lane >> 3);
    int n  = py * WW + px;

    float x = (float)px + 0.5f;
    float y = (float)py + 0.5f;

    const H8* cp = (const H8*)(curT + (size_t)n * CC);
    H8 cA = cp[0], cB = cp[1];
    // d is wave-uniform; force scalar load of the depth
    float depth = depths[__builtin_amdgcn_readfirstlane(d)];

    float acc = 0.f;
#pragma unroll 1
    for (int s = 0; s < SS; ++s) {
        const float* m = &mats[s * 12];    // s loop-uniform -> s_load
        float m0 = m[0], m1 = m[1], m2 = m[2], m3 = m[3], m4 = m[4], m5 = m[5];
        float m6 = m[6], m7 = m[7], m8 = m[8], m9 = m[9], m10 = m[10], m11 = m[11];
        float qx = m0 * x + m1 * y + m2;
        float qy = m3 * x + m4 * y + m5;
        float qz = m6 * x + m7 * y + m8;
        float pz = depth * qz + m11;
        bool ok = pz > 0.f;
        float r = __builtin_amdgcn_rcpf(pz + 1e-8f);   // u = px/(z+EPS) per ref
        float u = (depth * qx + m9)  * r - 0.5f;
        float v = (depth * qy + m10) * r - 0.5f;
        // wave-uniform skip: contribution is exactly 0 when z<=0 or all 4 taps OOB
        bool contrib = ok && (u > -1.f) && (u < (float)WW) && (v > -1.f) && (v < (float)HH);
        if (__ballot(contrib) == 0ull) continue;
        // float-side clamps keep both taps of each pair inside the padded image
        // and in the zero border when OOB (v_med3_f32); !ok -> far border
        float uc = ok ? fminf(fmaxf(u, -2.0f), 96.5f) : -2.0f;
        float vc = ok ? fminf(fmaxf(v, -1.0f), 64.5f) : -1.0f;
        float x0f = floorf(uc), y0f = floorf(vc);
        float wx = uc - x0f, wy = vc - y0f;
        int x0p = (int)x0f + 2;                  // [0, 98]
        int y0p = (int)y0f + 1;                  // [0, 65]
        int y1p = min(y0p + 1, PH - 1);          // [1, 65]
        const _Float16* sbase = srcT + (size_t)s * (PN * CC);
        const H8* r0 = (const H8*)(sbase + (size_t)(y0p * PW + x0p) * CC);
        const H8* r1 = (const H8*)(sbase + (size_t)(y1p * PW + x0p) * CC);
        H8 a0 = r0[0], a1 = r0[1], a2 = r0[2], a3 = r0[3];   // row0: left|right tap
        H8 b0 = r1[0], b1 = r1[1], b2 = r1[2], b3 = r1[3];   // row1: left|right tap
        float dL0 = 0.f, dR0 = 0.f, dL1 = 0.f, dR1 = 0.f;
#pragma unroll
        for (int q = 0; q < 4; ++q) {
            dL0 = __builtin_amdgcn_fdot2(a0.v[q], cA.v[q], dL0, false);
            dL0 = __builtin_amdgcn_fdot2(a1.v[q], cB.v[q], dL0, false);
            dR0 = __builtin_amdgcn_fdot2(a2.v[q], cA.v[q], dR0, false);
            dR0 = __builtin_amdgcn_fdot2(a3.v[q], cB.v[q], dR0, false);
            dL1 = __builtin_amdgcn_fdot2(b0.v[q], cA.v[q], dL1, false);
            dL1 = __builtin_amdgcn_fdot2(b1.v[q], cB.v[q], dL1, false);
            dR1 = __builtin_amdgcn_fdot2(b2.v[q], cA.v[q], dR1, false);
            dR1 = __builtin_amdgcn_fdot2(b3.v[q], cB.v[q], dR1, false);
        }
        float d0 = dL0 + wx * (dR0 - dL0);
        float d1 = dL1 + wx * (dR1 - dL1);
        acc += d0 + wy * (d1 - d0);
    }
    out[(size_t)d * NN + n] = acc;                      // cost_volume
    out[(size_t)DD * NN + (size_t)d * NN + n] = depth;  // depth_planes
}

extern "C" void kernel_launch(void* const* d_in, const int* in_sizes, int n_in,
                              void* d_out, int out_size, void* d_ws, size_t ws_size,
                              hipStream_t stream) {
    const float* cur  = (const float*)d_in[0];
    const float* src  = (const float*)d_in[1];
    const float* ext  = (const float*)d_in[2];
    const float* Ks   = (const float*)d_in[3];
    const float* invK = (const float*)d_in[4];
    const float* mn   = (const float*)d_in[5];
    const float* mx   = (const float*)d_in[6];
    float* out = (float*)d_out;

    char* ws = (char*)d_ws;
    _Float16* srcT = (_Float16*)ws;                     // S*PN*C halfs ≈ 1.69 MB
    _Float16* curT = srcT + (size_t)SS * PN * CC;       // N*C halfs
    float* mats    = (float*)(curT + (size_t)NN * CC);  // 96
    float* depths  = mats + SS * 12;                    // 64

    int prepThreads = SS * PN + NN;                     // 58944
    int prepBlocks = (prepThreads + 255) / 256;         // 231
    prep_kernel<<<prepBlocks, 256, 0, stream>>>(cur, src, ext, Ks, invK, mn, mx,
                                                srcT, curT, mats, depths);
    cost_kernel<<<(DD / 4) * (WW / 8) * (HH / 8), 256, 0, stream>>>(curT, srcT, mats, depths, out);
}